// Round 1
// baseline (953.329 us; speedup 1.0000x reference)
//
#include <hip/hip_runtime.h>

// RadarRnn1: 4-layer tanh RNN (B=512,S=1024,IN=64,H=32) + per-step FC + softmax over S.
// Strategy: batch-split blocks (2 batch/block), layer-pipelined wave groups
// (wave = one (layer, batch) pair; group l works on t = tick - l), weights in
// registers (ks=2 split of the K dim), h vectors through 2KB of LDS with a
// raw s_barrier (no vmcnt drain) so the distance-4 x-prefetch ring survives.

#define BB 512
#define SS 1024
#define INF 64
#define HH 32
#define LL 4

__device__ __forceinline__ void sync_lds() {
  // lgkmcnt(0) only; deliberately NOT vmcnt(0) so in-flight global loads
  // (x prefetch ring) stay outstanding across the barrier.
  asm volatile("s_waitcnt lgkmcnt(0)\n\ts_barrier" ::: "memory");
}

__global__ __launch_bounds__(512, 2) void rnn_kernel(
    const float* __restrict__ x, const float* __restrict__ h_state,
    const float* __restrict__ W_ih0, const float* __restrict__ W_ih_rest,
    const float* __restrict__ W_hh, const float* __restrict__ b_ih,
    const float* __restrict__ b_hh, const float* __restrict__ fc_w,
    const float* __restrict__ fc_b, float* __restrict__ out) {
  // hbuf[layer][parity][b_local][h] : h_l^t lives in parity t&1
  __shared__ float hbuf[LL][2][2][HH];
  // xlds[parity][b_local][k] : x_t lives in parity t&1 (written/read only by group 0)
  __shared__ float xlds[2][2][INF];

  const int tid  = threadIdx.x;
  const int wave = tid >> 6;
  const int lane = tid & 63;
  const int l    = wave >> 1;            // layer group 0..3
  const int bl   = wave & 1;             // local batch 0..1
  const int b    = blockIdx.x * 2 + bl;  // global batch
  const int ks   = lane & 1;             // k-split half
  const int h    = lane >> 1;            // output unit 0..31

  // ---------------- weights into registers ----------------
  float4 wa[8];  // input-side weights: l==0 uses 8 (32 x-floats), else 4 (16 h-floats)
  float4 wb[4];  // recurrent weights (16 floats)
  if (l == 0) {
    const float4* p = (const float4*)(W_ih0 + h * INF + ks * 32);
#pragma unroll
    for (int j = 0; j < 8; ++j) wa[j] = p[j];
    const float4* q = (const float4*)(W_hh + h * HH + ks * 16);
#pragma unroll
    for (int j = 0; j < 4; ++j) wb[j] = q[j];
  } else {
    const float4* p = (const float4*)(W_ih_rest + ((l - 1) * HH + h) * HH + ks * 16);
#pragma unroll
    for (int j = 0; j < 4; ++j) wa[j] = p[j];
    const float4* q = (const float4*)(W_hh + (l * HH + h) * HH + ks * 16);
#pragma unroll
    for (int j = 0; j < 4; ++j) wb[j] = q[j];
#pragma unroll
    for (int j = 4; j < 8; ++j) wa[j] = make_float4(0.f, 0.f, 0.f, 0.f);
  }
  const float bias = b_ih[l * HH + h] + b_hh[l * HH + h];
  const float fcw  = fc_w[h];
  const float fcb  = fc_b[0];

  // initial hidden state -> parity 1 (read parity of t=0)
  if (ks == 0) hbuf[l][1][bl][h] = h_state[(l * BB + b) * HH + h];

  // ---------------- x prefetch ring (group 0 only) ----------------
  const float* xb = x + (size_t)b * SS * INF;
  float r0 = 0.f, r1 = 0.f, r2 = 0.f, r3 = 0.f;
  if (l == 0) {
    float tmp = xb[0 * INF + lane];
    r0 = xb[1 * INF + lane];
    r1 = xb[2 * INF + lane];
    r2 = xb[3 * INF + lane];
    r3 = xb[4 * INF + lane];
    xlds[0][bl][lane] = tmp;  // x[0] into parity 0
  }
  __syncthreads();  // full barrier once; publishes hbuf init + xlds[0]

  // ---------------- pipelined tick loop ----------------
  for (int T = 0; T < SS + LL - 1; ++T) {
    const int t = T - l;
    if (t >= 0 && t < SS) {
      const int pw = t & 1;      // parity of h_l^t (write) and of input x_t / h_{l-1}^t
      const int pr = pw ^ 1;     // parity of h_l^{t-1}
      float a0 = 0.f, a1 = 0.f, a2 = 0.f, a3 = 0.f;
      if (l == 0) {
        const float4* xs = (const float4*)&xlds[pw][bl][ks * 32];
        float4 iv[8];
#pragma unroll
        for (int j = 0; j < 8; ++j) iv[j] = xs[j];
#pragma unroll
        for (int j = 0; j < 8; ++j) {
          a0 += wa[j].x * iv[j].x; a1 += wa[j].y * iv[j].y;
          a2 += wa[j].z * iv[j].z; a3 += wa[j].w * iv[j].w;
        }
      } else {
        const float4* is = (const float4*)&hbuf[l - 1][pw][bl][ks * 16];
        float4 iv[4];
#pragma unroll
        for (int j = 0; j < 4; ++j) iv[j] = is[j];
#pragma unroll
        for (int j = 0; j < 4; ++j) {
          a0 += wa[j].x * iv[j].x; a1 += wa[j].y * iv[j].y;
          a2 += wa[j].z * iv[j].z; a3 += wa[j].w * iv[j].w;
        }
      }
      {
        const float4* hs = (const float4*)&hbuf[l][pr][bl][ks * 16];
        float4 hv[4];
#pragma unroll
        for (int j = 0; j < 4; ++j) hv[j] = hs[j];
#pragma unroll
        for (int j = 0; j < 4; ++j) {
          a0 += wb[j].x * hv[j].x; a1 += wb[j].y * hv[j].y;
          a2 += wb[j].z * hv[j].z; a3 += wb[j].w * hv[j].w;
        }
      }
      float acc = (a0 + a1) + (a2 + a3);
      acc += __shfl_xor(acc, 1);  // combine the two k-halves
      acc += bias;
      const float e    = __expf(2.0f * acc);
      const float hval = 1.0f - 2.0f / (e + 1.0f);  // tanh(acc)
      if (ks == 0) hbuf[l][pw][bl][h] = hval;
      if (l == 3) {
        float v = hval * fcw;
        v += __shfl_xor(v, 2);
        v += __shfl_xor(v, 4);
        v += __shfl_xor(v, 8);
        v += __shfl_xor(v, 16);
        v += __shfl_xor(v, 32);
        if (lane == 0) out[(size_t)b * SS + t] = v + fcb;  // logit (softmax later, in place)
      }
      if (t == SS - 1 && ks == 0)
        out[(size_t)BB * SS + (l * BB + b) * HH + h] = hval;  // h_finals [L,B,H]
    }
    // x streaming pipeline: write x[T+1] to LDS, shift ring, issue load for x[T+5]
    if (l == 0 && T < SS - 1) {
      xlds[(T + 1) & 1][bl][lane] = r0;
      r0 = r1; r1 = r2; r2 = r3;
      int tl = T + 5; tl = (tl < SS) ? tl : (SS - 1);
      r3 = xb[tl * INF + lane];
    }
    sync_lds();
  }
}

__global__ __launch_bounds__(256) void softmax_kernel(float* __restrict__ out) {
  __shared__ float red[8];
  const int row = blockIdx.x;
  float* p = out + (size_t)row * SS;
  const int tid = threadIdx.x;
  float4 v = ((const float4*)p)[tid];  // 256 threads x 4 = 1024 logits
  float m = fmaxf(fmaxf(v.x, v.y), fmaxf(v.z, v.w));
#pragma unroll
  for (int d = 32; d >= 1; d >>= 1) m = fmaxf(m, __shfl_xor(m, d));
  if ((tid & 63) == 0) red[tid >> 6] = m;
  __syncthreads();
  m = fmaxf(fmaxf(red[0], red[1]), fmaxf(red[2], red[3]));
  const float e0 = __expf(v.x - m), e1 = __expf(v.y - m);
  const float e2 = __expf(v.z - m), e3 = __expf(v.w - m);
  float s = (e0 + e1) + (e2 + e3);
#pragma unroll
  for (int d = 32; d >= 1; d >>= 1) s += __shfl_xor(s, d);
  if ((tid & 63) == 0) red[4 + (tid >> 6)] = s;
  __syncthreads();
  s = (red[4] + red[5]) + (red[6] + red[7]);
  const float inv = 1.0f / s;
  float4 o;
  o.x = e0 * inv; o.y = e1 * inv; o.z = e2 * inv; o.w = e3 * inv;
  ((float4*)p)[tid] = o;
}

extern "C" void kernel_launch(void* const* d_in, const int* in_sizes, int n_in,
                              void* d_out, int out_size, void* d_ws, size_t ws_size,
                              hipStream_t stream) {
  const float* x         = (const float*)d_in[0];
  const float* h_state   = (const float*)d_in[1];
  const float* W_ih0     = (const float*)d_in[2];
  const float* W_ih_rest = (const float*)d_in[3];
  const float* W_hh      = (const float*)d_in[4];
  const float* b_ih      = (const float*)d_in[5];
  const float* b_hh      = (const float*)d_in[6];
  const float* fc_w      = (const float*)d_in[7];
  const float* fc_b      = (const float*)d_in[8];
  float* out = (float*)d_out;

  hipLaunchKernelGGL(rnn_kernel, dim3(BB / 2), dim3(512), 0, stream,
                     x, h_state, W_ih0, W_ih_rest, W_hh, b_ih, b_hh, fc_w, fc_b, out);
  hipLaunchKernelGGL(softmax_kernel, dim3(BB), dim3(256), 0, stream, out);
}

// Round 2
// 911.076 us; speedup vs baseline: 1.0464x; 1.0464x over previous
//
#include <hip/hip_runtime.h>

// RadarRnn1: 4-layer tanh RNN (B=512,S=1024,IN=64,H=32) + per-step FC + softmax over S.
// R2: replace all __shfl_xor (ds_swizzle, ~120cy dependent latency each) with
// DPP v_add chains (~8cy each). The l==3 wave's 6-deep swizzle chain was the
// per-tick critical path (R1: 1940 cy/tick measured vs ~350 cy of real work).

#define BB 512
#define SS 1024
#define INF 64
#define HH 32
#define LL 4

__device__ __forceinline__ void sync_lds() {
  // lgkmcnt(0) only; deliberately NOT vmcnt(0) so in-flight global loads
  // (x prefetch ring) stay outstanding across the barrier.
  asm volatile("s_waitcnt lgkmcnt(0)\n\ts_barrier" ::: "memory");
}

// v = v + dpp_mov(v, CTRL); bound_ctrl=1 -> out-of-range lanes contribute 0.
template <int CTRL>
__device__ __forceinline__ float dpp_add(float v) {
  int y = __builtin_amdgcn_update_dpp(0, __float_as_int(v), CTRL, 0xF, 0xF, true);
  return v + __int_as_float(y);
}

__global__ __launch_bounds__(512, 2) void rnn_kernel(
    const float* __restrict__ x, const float* __restrict__ h_state,
    const float* __restrict__ W_ih0, const float* __restrict__ W_ih_rest,
    const float* __restrict__ W_hh, const float* __restrict__ b_ih,
    const float* __restrict__ b_hh, const float* __restrict__ fc_w,
    const float* __restrict__ fc_b, float* __restrict__ out) {
  // hbuf[layer][parity][b_local][h] : h_l^t lives in parity t&1
  __shared__ float hbuf[LL][2][2][HH];
  // xlds[parity][b_local][k] : x_t lives in parity t&1 (written/read only by group 0)
  __shared__ float xlds[2][2][INF];

  const int tid  = threadIdx.x;
  const int wave = tid >> 6;
  const int lane = tid & 63;
  const int l    = wave >> 1;            // layer group 0..3
  const int bl   = wave & 1;             // local batch 0..1
  const int b    = blockIdx.x * 2 + bl;  // global batch
  const int ks   = lane & 1;             // k-split half
  const int h    = lane >> 1;            // output unit 0..31

  // ---------------- weights into registers ----------------
  float4 wa[8];  // input-side weights: l==0 uses 8 (32 x-floats), else 4 (16 h-floats)
  float4 wb[4];  // recurrent weights (16 floats)
  if (l == 0) {
    const float4* p = (const float4*)(W_ih0 + h * INF + ks * 32);
#pragma unroll
    for (int j = 0; j < 8; ++j) wa[j] = p[j];
    const float4* q = (const float4*)(W_hh + h * HH + ks * 16);
#pragma unroll
    for (int j = 0; j < 4; ++j) wb[j] = q[j];
  } else {
    const float4* p = (const float4*)(W_ih_rest + ((l - 1) * HH + h) * HH + ks * 16);
#pragma unroll
    for (int j = 0; j < 4; ++j) wa[j] = p[j];
    const float4* q = (const float4*)(W_hh + (l * HH + h) * HH + ks * 16);
#pragma unroll
    for (int j = 0; j < 4; ++j) wb[j] = q[j];
#pragma unroll
    for (int j = 4; j < 8; ++j) wa[j] = make_float4(0.f, 0.f, 0.f, 0.f);
  }
  const float bias  = b_ih[l * HH + h] + b_hh[l * HH + h];
  const float fcwh  = fc_w[h] * 0.5f;  // both ks lanes hold hval -> sum over 64 lanes = 2x
  const float fcb   = fc_b[0];
  float* const outrow = out + (size_t)b * SS;

  // initial hidden state -> parity 1 (read parity of t=0)
  if (ks == 0) hbuf[l][1][bl][h] = h_state[(l * BB + b) * HH + h];

  // ---------------- x prefetch ring (group 0 only) ----------------
  const float* xb = x + (size_t)b * SS * INF;
  float r0 = 0.f, r1 = 0.f, r2 = 0.f, r3 = 0.f;
  if (l == 0) {
    float tmp = xb[0 * INF + lane];
    r0 = xb[1 * INF + lane];
    r1 = xb[2 * INF + lane];
    r2 = xb[3 * INF + lane];
    r3 = xb[4 * INF + lane];
    xlds[0][bl][lane] = tmp;  // x[0] into parity 0
  }
  __syncthreads();  // full barrier once; publishes hbuf init + xlds[0]

  // ---------------- pipelined tick loop ----------------
  for (int T = 0; T < SS + LL - 1; ++T) {
    const int t = T - l;
    if (t >= 0 && t < SS) {
      const int pw = t & 1;      // parity of h_l^t (write) and of input x_t / h_{l-1}^t
      const int pr = pw ^ 1;     // parity of h_l^{t-1}
      float a0 = 0.f, a1 = 0.f, a2 = 0.f, a3 = 0.f;
      if (l == 0) {
        const float4* xs = (const float4*)&xlds[pw][bl][ks * 32];
        float4 iv[8];
#pragma unroll
        for (int j = 0; j < 8; ++j) iv[j] = xs[j];
#pragma unroll
        for (int j = 0; j < 8; ++j) {
          a0 += wa[j].x * iv[j].x; a1 += wa[j].y * iv[j].y;
          a2 += wa[j].z * iv[j].z; a3 += wa[j].w * iv[j].w;
        }
      } else {
        const float4* is = (const float4*)&hbuf[l - 1][pw][bl][ks * 16];
        float4 iv[4];
#pragma unroll
        for (int j = 0; j < 4; ++j) iv[j] = is[j];
#pragma unroll
        for (int j = 0; j < 4; ++j) {
          a0 += wa[j].x * iv[j].x; a1 += wa[j].y * iv[j].y;
          a2 += wa[j].z * iv[j].z; a3 += wa[j].w * iv[j].w;
        }
      }
      {
        const float4* hs = (const float4*)&hbuf[l][pr][bl][ks * 16];
        float4 hv[4];
#pragma unroll
        for (int j = 0; j < 4; ++j) hv[j] = hs[j];
#pragma unroll
        for (int j = 0; j < 4; ++j) {
          a0 += wb[j].x * hv[j].x; a1 += wb[j].y * hv[j].y;
          a2 += wb[j].z * hv[j].z; a3 += wb[j].w * hv[j].w;
        }
      }
      float acc = (a0 + a1) + (a2 + a3);
      acc = dpp_add<0xB1>(acc);  // quad_perm [1,0,3,2]: combine the two ks halves
      acc += bias;
      const float e    = __expf(2.0f * acc);
      const float hval = 1.0f - 2.0f / (e + 1.0f);  // tanh(acc)
      if (ks == 0) hbuf[l][pw][bl][h] = hval;
      if (l == 3) {
        // FC reduce over 64 lanes via DPP cascade (VALU, no LDS): lane 63 ends
        // with the total. Off the recurrence path (hbuf write already issued).
        float v = hval * fcwh;
        v = dpp_add<0x111>(v);  // row_shr:1
        v = dpp_add<0x112>(v);  // row_shr:2
        v = dpp_add<0x114>(v);  // row_shr:4
        v = dpp_add<0x118>(v);  // row_shr:8
        v = dpp_add<0x142>(v);  // row_bcast:15
        v = dpp_add<0x143>(v);  // row_bcast:31
        if (lane == 63) outrow[t] = v + fcb;  // logit (softmax later, in place)
      }
      if (t == SS - 1 && ks == 0)
        out[(size_t)BB * SS + (l * BB + b) * HH + h] = hval;  // h_finals [L,B,H]
    }
    // x streaming pipeline: write x[T+1] to LDS, shift ring, issue load for x[T+5]
    if (l == 0 && T < SS - 1) {
      xlds[(T + 1) & 1][bl][lane] = r0;
      r0 = r1; r1 = r2; r2 = r3;
      int tl = T + 5; tl = (tl < SS) ? tl : (SS - 1);
      r3 = xb[tl * INF + lane];
    }
    sync_lds();
  }
}

__global__ __launch_bounds__(256) void softmax_kernel(float* __restrict__ out) {
  __shared__ float red[8];
  const int row = blockIdx.x;
  float* p = out + (size_t)row * SS;
  const int tid = threadIdx.x;
  float4 v = ((const float4*)p)[tid];  // 256 threads x 4 = 1024 logits
  float m = fmaxf(fmaxf(v.x, v.y), fmaxf(v.z, v.w));
#pragma unroll
  for (int d = 32; d >= 1; d >>= 1) m = fmaxf(m, __shfl_xor(m, d));
  if ((tid & 63) == 0) red[tid >> 6] = m;
  __syncthreads();
  m = fmaxf(fmaxf(red[0], red[1]), fmaxf(red[2], red[3]));
  const float e0 = __expf(v.x - m), e1 = __expf(v.y - m);
  const float e2 = __expf(v.z - m), e3 = __expf(v.w - m);
  float s = (e0 + e1) + (e2 + e3);
#pragma unroll
  for (int d = 32; d >= 1; d >>= 1) s += __shfl_xor(s, d);
  if ((tid & 63) == 0) red[4 + (tid >> 6)] = s;
  __syncthreads();
  s = (red[4] + red[5]) + (red[6] + red[7]);
  const float inv = 1.0f / s;
  float4 o;
  o.x = e0 * inv; o.y = e1 * inv; o.z = e2 * inv; o.w = e3 * inv;
  ((float4*)p)[tid] = o;
}

extern "C" void kernel_launch(void* const* d_in, const int* in_sizes, int n_in,
                              void* d_out, int out_size, void* d_ws, size_t ws_size,
                              hipStream_t stream) {
  const float* x         = (const float*)d_in[0];
  const float* h_state   = (const float*)d_in[1];
  const float* W_ih0     = (const float*)d_in[2];
  const float* W_ih_rest = (const float*)d_in[3];
  const float* W_hh      = (const float*)d_in[4];
  const float* b_ih      = (const float*)d_in[5];
  const float* b_hh      = (const float*)d_in[6];
  const float* fc_w      = (const float*)d_in[7];
  const float* fc_b      = (const float*)d_in[8];
  float* out = (float*)d_out;

  hipLaunchKernelGGL(rnn_kernel, dim3(BB / 2), dim3(512), 0, stream,
                     x, h_state, W_ih0, W_ih_rest, W_hh, b_ih, b_hh, fc_w, fc_b, out);
  hipLaunchKernelGGL(softmax_kernel, dim3(BB), dim3(256), 0, stream, out);
}

// Round 3
// 762.301 us; speedup vs baseline: 1.2506x; 1.1952x over previous
//
#include <hip/hip_runtime.h>

// RadarRnn1: 4-layer tanh RNN (B=512,S=1024,IN=64,H=32) + per-step FC + softmax over S.
// R3: R2's VGPR x-ring forced a per-tick s_waitcnt vmcnt(0) (register shift of a
// load result with distance-1) -> ~1300 cy/tick stall propagated through the
// barrier. Replace with global_load_lds (no VGPR result, no compiler wait) into
// an 8-slot LDS ring, prefetch distance 6, manual s_waitcnt vmcnt(5).

#define BB 512
#define SS 1024
#define INF 64
#define HH 32
#define LL 4

__device__ __forceinline__ void sync_lds() {
  // lgkmcnt(0) only; deliberately NOT vmcnt(0) so in-flight global_load_lds
  // (x prefetch ring) stay outstanding across the barrier.
  asm volatile("s_waitcnt lgkmcnt(0)\n\ts_barrier" ::: "memory");
}

// v = v + dpp_mov(v, CTRL); bound_ctrl=1 -> out-of-range lanes contribute 0.
template <int CTRL>
__device__ __forceinline__ float dpp_add(float v) {
  int y = __builtin_amdgcn_update_dpp(0, __float_as_int(v), CTRL, 0xF, 0xF, true);
  return v + __int_as_float(y);
}

__global__ __launch_bounds__(512, 2) void rnn_kernel(
    const float* __restrict__ x, const float* __restrict__ h_state,
    const float* __restrict__ W_ih0, const float* __restrict__ W_ih_rest,
    const float* __restrict__ W_hh, const float* __restrict__ b_ih,
    const float* __restrict__ b_hh, const float* __restrict__ fc_w,
    const float* __restrict__ fc_b, float* __restrict__ out) {
  // hbuf[layer][parity][b_local][h] : h_l^t lives in parity t&1
  __shared__ float hbuf[LL][2][2][HH];
  // xlds[slot][b_local][k] : x_t lives in slot t&7, filled by global_load_lds
  __shared__ float xlds[8][2][INF];

  const int tid  = threadIdx.x;
  const int wave = tid >> 6;
  const int lane = tid & 63;
  const int l    = wave >> 1;            // layer group 0..3
  const int bl   = wave & 1;             // local batch 0..1
  const int b    = blockIdx.x * 2 + bl;  // global batch
  const int ks   = lane & 1;             // k-split half
  const int h    = lane >> 1;            // output unit 0..31

  // ---------------- weights into registers ----------------
  float4 wa[8];  // input-side weights: l==0 uses 8 (32 x-floats), else 4 (16 h-floats)
  float4 wb[4];  // recurrent weights (16 floats)
  if (l == 0) {
    const float4* p = (const float4*)(W_ih0 + h * INF + ks * 32);
#pragma unroll
    for (int j = 0; j < 8; ++j) wa[j] = p[j];
    const float4* q = (const float4*)(W_hh + h * HH + ks * 16);
#pragma unroll
    for (int j = 0; j < 4; ++j) wb[j] = q[j];
  } else {
    const float4* p = (const float4*)(W_ih_rest + ((l - 1) * HH + h) * HH + ks * 16);
#pragma unroll
    for (int j = 0; j < 4; ++j) wa[j] = p[j];
    const float4* q = (const float4*)(W_hh + (l * HH + h) * HH + ks * 16);
#pragma unroll
    for (int j = 0; j < 4; ++j) wb[j] = q[j];
#pragma unroll
    for (int j = 4; j < 8; ++j) wa[j] = make_float4(0.f, 0.f, 0.f, 0.f);
  }
  const float bias  = b_ih[l * HH + h] + b_hh[l * HH + h];
  const float fcwh  = fc_w[h] * 0.5f;  // both ks lanes hold hval -> sum over 64 lanes = 2x
  const float fcb   = fc_b[0];
  float* const outrow = out + (size_t)b * SS;

  // initial hidden state -> parity 1 (read parity of t=0)
  if (ks == 0) hbuf[l][1][bl][h] = h_state[(l * BB + b) * HH + h];

  const float* xb = x + (size_t)b * SS * INF;
  __syncthreads();  // publishes hbuf init (drains everything; loop barriers won't)

  // ---------------- x prefill: 6 in-flight global_load_lds (group 0 only) ---
  if (l == 0) {
#pragma unroll
    for (int j = 0; j < 6; ++j) {
      __builtin_amdgcn_global_load_lds(
          (const __attribute__((address_space(1))) void*)(xb + j * INF + lane),
          (__attribute__((address_space(3))) void*)&xlds[j][bl][0], 4, 0, 0);
    }
  }

  // ---------------- pipelined tick loop ----------------
  for (int T = 0; T < SS + LL - 1; ++T) {
    const int t = T - l;
    if (t >= 0 && t < SS) {
      const int pw = t & 1;      // parity of h_l^t (write) and of input h_{l-1}^t
      const int pr = pw ^ 1;     // parity of h_l^{t-1}
      float a0 = 0.f, a1 = 0.f, a2 = 0.f, a3 = 0.f;
      if (l == 0) {
        // wait for the oldest of 6 in-flight x loads (slot t&7, issued 6 ticks ago)
        asm volatile("s_waitcnt vmcnt(5)" ::: "memory");
        const float4* xs = (const float4*)&xlds[t & 7][bl][ks * 32];
        float4 iv[8];
#pragma unroll
        for (int j = 0; j < 8; ++j) iv[j] = xs[j];
#pragma unroll
        for (int j = 0; j < 8; ++j) {
          a0 += wa[j].x * iv[j].x; a1 += wa[j].y * iv[j].y;
          a2 += wa[j].z * iv[j].z; a3 += wa[j].w * iv[j].w;
        }
      } else {
        const float4* is = (const float4*)&hbuf[l - 1][pw][bl][ks * 16];
        float4 iv[4];
#pragma unroll
        for (int j = 0; j < 4; ++j) iv[j] = is[j];
#pragma unroll
        for (int j = 0; j < 4; ++j) {
          a0 += wa[j].x * iv[j].x; a1 += wa[j].y * iv[j].y;
          a2 += wa[j].z * iv[j].z; a3 += wa[j].w * iv[j].w;
        }
      }
      {
        const float4* hs = (const float4*)&hbuf[l][pr][bl][ks * 16];
        float4 hv[4];
#pragma unroll
        for (int j = 0; j < 4; ++j) hv[j] = hs[j];
#pragma unroll
        for (int j = 0; j < 4; ++j) {
          a0 += wb[j].x * hv[j].x; a1 += wb[j].y * hv[j].y;
          a2 += wb[j].z * hv[j].z; a3 += wb[j].w * hv[j].w;
        }
      }
      float acc = (a0 + a1) + (a2 + a3);
      acc = dpp_add<0xB1>(acc);  // quad_perm [1,0,3,2]: combine the two ks halves
      acc += bias;
      const float e    = __expf(2.0f * acc);
      const float hval = 1.0f - 2.0f / (e + 1.0f);  // tanh(acc)
      if (ks == 0) hbuf[l][pw][bl][h] = hval;
      if (l == 3) {
        // FC reduce over 64 lanes via DPP cascade (VALU, no LDS): lane 63 ends
        // with the total. Off the recurrence path (hbuf write already issued).
        float v = hval * fcwh;
        v = dpp_add<0x111>(v);  // row_shr:1
        v = dpp_add<0x112>(v);  // row_shr:2
        v = dpp_add<0x114>(v);  // row_shr:4
        v = dpp_add<0x118>(v);  // row_shr:8
        v = dpp_add<0x142>(v);  // row_bcast:15
        v = dpp_add<0x143>(v);  // row_bcast:31
        if (lane == 63) outrow[t] = v + fcb;  // logit (softmax later, in place)
      }
      if (t == SS - 1 && ks == 0)
        out[(size_t)BB * SS + (l * BB + b) * HH + h] = hval;  // h_finals [L,B,H]
    }
    // x streaming: issue load for t=T+6 into slot (T+6)&7 (consumed 2 barriers
    // ago -> its ds_reads are complete; safe to overwrite). Clamp keeps the
    // 6-in-flight vmcnt invariant exact through the tail.
    if (l == 0) {
      int tl = T + 6; tl = (tl < SS) ? tl : (SS - 1);
      __builtin_amdgcn_global_load_lds(
          (const __attribute__((address_space(1))) void*)(xb + tl * INF + lane),
          (__attribute__((address_space(3))) void*)&xlds[(T + 6) & 7][bl][0], 4, 0, 0);
    }
    sync_lds();
  }
}

__global__ __launch_bounds__(256) void softmax_kernel(float* __restrict__ out) {
  __shared__ float red[8];
  const int row = blockIdx.x;
  float* p = out + (size_t)row * SS;
  const int tid = threadIdx.x;
  float4 v = ((const float4*)p)[tid];  // 256 threads x 4 = 1024 logits
  float m = fmaxf(fmaxf(v.x, v.y), fmaxf(v.z, v.w));
#pragma unroll
  for (int d = 32; d >= 1; d >>= 1) m = fmaxf(m, __shfl_xor(m, d));
  if ((tid & 63) == 0) red[tid >> 6] = m;
  __syncthreads();
  m = fmaxf(fmaxf(red[0], red[1]), fmaxf(red[2], red[3]));
  const float e0 = __expf(v.x - m), e1 = __expf(v.y - m);
  const float e2 = __expf(v.z - m), e3 = __expf(v.w - m);
  float s = (e0 + e1) + (e2 + e3);
#pragma unroll
  for (int d = 32; d >= 1; d >>= 1) s += __shfl_xor(s, d);
  if ((tid & 63) == 0) red[4 + (tid >> 6)] = s;
  __syncthreads();
  s = (red[4] + red[5]) + (red[6] + red[7]);
  const float inv = 1.0f / s;
  float4 o;
  o.x = e0 * inv; o.y = e1 * inv; o.z = e2 * inv; o.w = e3 * inv;
  ((float4*)p)[tid] = o;
}

extern "C" void kernel_launch(void* const* d_in, const int* in_sizes, int n_in,
                              void* d_out, int out_size, void* d_ws, size_t ws_size,
                              hipStream_t stream) {
  const float* x         = (const float*)d_in[0];
  const float* h_state   = (const float*)d_in[1];
  const float* W_ih0     = (const float*)d_in[2];
  const float* W_ih_rest = (const float*)d_in[3];
  const float* W_hh      = (const float*)d_in[4];
  const float* b_ih      = (const float*)d_in[5];
  const float* b_hh      = (const float*)d_in[6];
  const float* fc_w      = (const float*)d_in[7];
  const float* fc_b      = (const float*)d_in[8];
  float* out = (float*)d_out;

  hipLaunchKernelGGL(rnn_kernel, dim3(BB / 2), dim3(512), 0, stream,
                     x, h_state, W_ih0, W_ih_rest, W_hh, b_ih, b_hh, fc_w, fc_b, out);
  hipLaunchKernelGGL(softmax_kernel, dim3(BB), dim3(256), 0, stream, out);
}